// Round 16
// baseline (803.547 us; speedup 1.0000x reference)
//
#include <hip/hip_runtime.h>
#include <hip/hip_bf16.h>
#include <math.h>

typedef float f32x4 __attribute__((ext_vector_type(4)));
typedef float f32x2 __attribute__((ext_vector_type(2)));
typedef __bf16 bf16x8 __attribute__((ext_vector_type(8)));
typedef unsigned short u16x4 __attribute__((ext_vector_type(4)));

// ---------------- LDS map (40960 B exactly -> 4 blocks/CU) ----------------
// SA 24576 | RQ/RK/RVT/RO 4x4096 | MLP: G double-buffer 2x8192 overlays RQ..RO
#define SA_B  0
#define RQ_B  24576
#define RK_B  28672
#define RVT_B 32768
#define RO_B  36864
#define RG_B  24576
#define SMEM  40960

__device__ __forceinline__ int sa_off(int row,int byte){ return SA_B + row*384 + (byte ^ ((row&7)<<4)); }
__device__ __forceinline__ int vt_off(int row,int byte){ return RVT_B+ row*128 + (byte ^ ((row&7)<<4)); }
__device__ __forceinline__ int gq_off(int row,int byte){ return row*128 + (byte ^ ((row&7)<<4)); }  // G chunk-64: [64 tok][128B]
__device__ __forceinline__ int qp_off(int base,int tok,int byte){
  return base + (tok>>1)*128 + (tok&1)*64 + (byte ^ (((tok>>1)&3)<<4));
}
__device__ __forceinline__ unsigned short f2b(float x){ return __builtin_bit_cast(unsigned short, (__bf16)x); }

union U64 { unsigned long long u; u16x4 v; };
union U128 { unsigned long long q[2]; bf16x8 b; };

// Transpose + cast weights to bf16 [N][K]
__global__ void prep_weights(const float* __restrict__ wqkv, const float* __restrict__ wproj,
                             const float* __restrict__ wmlp1, const float* __restrict__ wmlp2,
                             unsigned short* __restrict__ ws){
  int idx = blockIdx.x*256 + threadIdx.x;
  if (idx < 110592){ int n=idx/192, k=idx%192; ws[idx] = f2b(wqkv[k*576+n]); }
  else if (idx < 147456){ int i=idx-110592; int n=i/192, k=i%192; ws[idx] = f2b(wproj[k*192+n]); }
  else if (idx < 294912){ int i=idx-147456; int n=i/192, k=i%192; ws[idx] = f2b(wmlp1[k*768+n]); }
  else if (idx < 442368){ int i=idx-294912; int n=i/768, k=i%768; ws[idx] = f2b(wmlp2[k*192+n]); }
}

// K2. Thread (w,lg,l16): owns toks {16tt+l16} x chs {48w+16mt+4lg+r}. 40KB LDS, 4 blocks/CU.
__global__ void __launch_bounds__(256, 4) winblock(
    const float* __restrict__ xin, float* __restrict__ outp,
    const float* __restrict__ bqkv, const float* __restrict__ bproj,
    const float* __restrict__ ln1g, const float* __restrict__ ln1b,
    const float* __restrict__ ln2g, const float* __restrict__ ln2b,
    const float* __restrict__ bmlp1, const float* __restrict__ bmlp2,
    const unsigned short* __restrict__ wqkvT, const unsigned short* __restrict__ wprojT,
    const unsigned short* __restrict__ wmlp1T, const unsigned short* __restrict__ wmlp2T)
{
  __shared__ __align__(16) char sm[SMEM];
  const int tid=threadIdx.x, w=tid>>6, lg=(tid>>4)&3, l16=tid&15;
  const int wid=blockIdx.x;
  const int bb=wid>>10, wh=(wid>>5)&31, wwi=wid&31;
  const size_t imgoff=(size_t)bb*192*65536 + (size_t)(wh*8)*256 + (size_t)(wwi*8);
  f32x2* red = (f32x2*)(sm + RQ_B);

  // ---- residual t[mt][tt]: ch 48w+16mt+4lg+r, tok 16tt+l16 ----
  f32x4 t[3][4];
  #pragma unroll
  for(int mt=0;mt<3;++mt)
    #pragma unroll
    for(int tt=0;tt<4;++tt){
      const int T=16*tt+l16, tp=(T>>3)*256+(T&7);
      #pragma unroll
      for(int r=0;r<4;++r)
        t[mt][tt][r]=xin[imgoff+(size_t)(48*w+16*mt+4*lg+r)*65536+tp];
    }

  // ---- LayerNorm -> bf16 into SA (contains one internal barrier) ----
  auto layernorm = [&](const float* gg, const float* bbv){
    float s[4], s2[4];
    #pragma unroll
    for(int tt=0;tt<4;++tt){
      float a=0.f,b2=0.f;
      #pragma unroll
      for(int mt=0;mt<3;++mt){
        #pragma unroll
        for(int r=0;r<4;++r){ a+=t[mt][tt][r]; b2+=t[mt][tt][r]*t[mt][tt][r]; }
      }
      a+=__shfl_xor(a,16); a+=__shfl_xor(a,32);
      b2+=__shfl_xor(b2,16); b2+=__shfl_xor(b2,32);
      s[tt]=a; s2[tt]=b2;
    }
    if(lg==0) red[w*64 +  0+l16]=(f32x2){s[0],s2[0]};
    if(lg==1) red[w*64 + 16+l16]=(f32x2){s[1],s2[1]};
    if(lg==2) red[w*64 + 32+l16]=(f32x2){s[2],s2[2]};
    if(lg==3) red[w*64 + 48+l16]=(f32x2){s[3],s2[3]};
    __syncthreads();
    float mean[4], rstd[4];
    #pragma unroll
    for(int tt=0;tt<4;++tt){
      float S=0.f,S2=0.f;
      #pragma unroll
      for(int w2=0;w2<4;++w2){ f32x2 v=red[w2*64+16*tt+l16]; S+=v.x; S2+=v.y; }
      mean[tt]=S*(1.f/192.f);
      rstd[tt]=rsqrtf(S2*(1.f/192.f)-mean[tt]*mean[tt]+1e-5f);
    }
    #pragma unroll
    for(int mt=0;mt<3;++mt){
      const f32x4 g4=*(const f32x4*)(gg+48*w+16*mt+4*lg);
      const f32x4 b4=*(const f32x4*)(bbv+48*w+16*mt+4*lg);
      #pragma unroll
      for(int tt=0;tt<4;++tt){
        u16x4 pk;
        #pragma unroll
        for(int r=0;r<4;++r) pk[r]=f2b((t[mt][tt][r]-mean[tt])*rstd[tt]*g4[r]+b4[r]);
        *(u16x4*)(sm+sa_off(16*tt+l16,(48*w+16*mt+4*lg)*2))=pk;
      }
    }
  };

  layernorm(ln1g, ln1b);
  __syncthreads();   // h visible

  // ---- QKV producer: wave w -> ct=w>>1 (ch-half of head), tok-tiles {2(w&1),+1} ----
  // Weight fragments batched 9-at-a-time (3 ks) to keep loads in flight.
  const int ct=w>>1, tbase=2*(w&1);
  auto c1=[&](int hh){
    f32x4 qa[2],ka[2],va[2];
    #pragma unroll
    for(int i=0;i<2;++i){ qa[i]=(f32x4){0,0,0,0}; ka[i]=(f32x4){0,0,0,0}; va[i]=(f32x4){0,0,0,0}; }
    #pragma unroll
    for(int hf=0;hf<2;++hf){
      bf16x8 wq[3],wk[3],wv[3];
      #pragma unroll
      for(int k3=0;k3<3;++k3){
        const int ks=hf*3+k3;
        wq[k3]=*(const bf16x8*)(wqkvT+(      hh*32+ct*16+l16)*192+ks*32+lg*8);
        wk[k3]=*(const bf16x8*)(wqkvT+(192 + hh*32+ct*16+l16)*192+ks*32+lg*8);
        wv[k3]=*(const bf16x8*)(wqkvT+(384 + hh*32+ct*16+l16)*192+ks*32+lg*8);
      }
      #pragma unroll
      for(int k3=0;k3<3;++k3){
        const int ks=hf*3+k3;
        bf16x8 hfrag[2];
        #pragma unroll
        for(int i=0;i<2;++i) hfrag[i]=*(const bf16x8*)(sm+sa_off(16*(tbase+i)+l16, ks*64+lg*16));
        #pragma unroll
        for(int i=0;i<2;++i){
          qa[i]=__builtin_amdgcn_mfma_f32_16x16x32_bf16(wq[k3],hfrag[i],qa[i],0,0,0);  // D[qch][tok]
          ka[i]=__builtin_amdgcn_mfma_f32_16x16x32_bf16(wk[k3],hfrag[i],ka[i],0,0,0);
          va[i]=__builtin_amdgcn_mfma_f32_16x16x32_bf16(hfrag[i],wv[k3],va[i],0,0,0);  // D[tok][vch]
        }
      }
    }
    const f32x4 bq4=*(const f32x4*)(bqkv+      hh*32+ct*16+4*lg);
    const f32x4 bk4=*(const f32x4*)(bqkv+192 + hh*32+ct*16+4*lg);
    const float bv =bqkv[384 + hh*32+ct*16+l16];
    #pragma unroll
    for(int i=0;i<2;++i){
      const int tok=16*(tbase+i)+l16;
      u16x4 pq,pk,pv;
      #pragma unroll
      for(int r=0;r<4;++r){
        pq[r]=f2b(qa[i][r]+bq4[r]);
        pk[r]=f2b(ka[i][r]+bk4[r]);
        pv[r]=f2b(va[i][r]+bv);
      }
      *(u16x4*)(sm+qp_off(RQ_B,tok,32*ct+8*lg))=pq;                  // Q[tok][qch]
      *(u16x4*)(sm+qp_off(RK_B,tok,32*ct+8*lg))=pk;                  // K[tok][qch]
      *(u16x4*)(sm+vt_off(ct*16+l16,(16*(tbase+i)+4*lg)*2))=pv;      // VT[vch][tok]
    }
  };

  c1(0);
  __syncthreads();

  const float SM_C = 0.25503487f;  // log2(e)/sqrt(32), applied in f32 at exp2
  #pragma unroll 1
  for(int h=0;h<6;++h){
    // ---- S^T = K.Q (A=K rows=ktok, B=Q col=own q) ; softmax in-register ----
    {
      const int q=16*w+l16;
      const bf16x8 bqf=*(const bf16x8*)(sm+qp_off(RQ_B,q,lg*16));
      f32x4 sv[4];
      #pragma unroll
      for(int kt=0;kt<4;++kt){
        const bf16x8 akf=*(const bf16x8*)(sm+qp_off(RK_B,16*kt+l16,lg*16));
        sv[kt]=__builtin_amdgcn_mfma_f32_16x16x32_bf16(akf,bqf,(f32x4){0,0,0,0},0,0,0);
      }
      float mx=-3.0e38f;
      #pragma unroll
      for(int kt=0;kt<4;++kt){
        #pragma unroll
        for(int r=0;r<4;++r) mx=fmaxf(mx,sv[kt][r]);
      }
      mx=fmaxf(mx,__shfl_xor(mx,16)); mx=fmaxf(mx,__shfl_xor(mx,32));
      float sum=0.f;
      #pragma unroll
      for(int kt=0;kt<4;++kt){
        #pragma unroll
        for(int r=0;r<4;++r){ float e=exp2f((sv[kt][r]-mx)*SM_C); sv[kt][r]=e; sum+=e; }
      }
      sum+=__shfl_xor(sum,16); sum+=__shfl_xor(sum,32);
      const float rs=1.f/sum;
      U64 pk0,pk1,pk2,pk3;
      #pragma unroll
      for(int r=0;r<4;++r){ pk0.v[r]=f2b(sv[0][r]*rs); pk1.v[r]=f2b(sv[1][r]*rs);
                            pk2.v[r]=f2b(sv[2][r]*rs); pk3.v[r]=f2b(sv[3][r]*rs); }
      const int srcA = ((lg&1)<<5) + l16, srcB = srcA + 16;
      unsigned long long rA0=__shfl(pk0.u,srcA), rB0=__shfl(pk0.u,srcB);
      unsigned long long rA1=__shfl(pk1.u,srcA), rB1=__shfl(pk1.u,srcB);
      unsigned long long rA2=__shfl(pk2.u,srcA), rB2=__shfl(pk2.u,srcB);
      unsigned long long rA3=__shfl(pk3.u,srcA), rB3=__shfl(pk3.u,srcB);
      U128 pf0, pf1;
      pf0.q[0]=(lg<2)?rA0:rA1;  pf0.q[1]=(lg<2)?rB0:rB1;   // ktok 0..31
      pf1.q[0]=(lg<2)?rA2:rA3;  pf1.q[1]=(lg<2)?rB2:rB3;   // ktok 32..63
      // ---- PV: A=VT (rows d), B=P (col=own q) -> D[d][q]; write O[q][d] ----
      f32x4 ov[2]={(f32x4){0,0,0,0},(f32x4){0,0,0,0}};
      #pragma unroll
      for(int dt=0;dt<2;++dt){
        const bf16x8 av0=*(const bf16x8*)(sm+vt_off(16*dt+l16,lg*16));
        const bf16x8 av1=*(const bf16x8*)(sm+vt_off(16*dt+l16,64+lg*16));
        ov[dt]=__builtin_amdgcn_mfma_f32_16x16x32_bf16(av0,pf0.b,ov[dt],0,0,0);
        ov[dt]=__builtin_amdgcn_mfma_f32_16x16x32_bf16(av1,pf1.b,ov[dt],0,0,0);
      }
      #pragma unroll
      for(int dt=0;dt<2;++dt){
        u16x4 po;
        #pragma unroll
        for(int r=0;r<4;++r) po[r]=f2b(ov[dt][r]);
        *(u16x4*)(sm+qp_off(RO_B,q,32*dt+8*lg))=po;   // own q row
      }
    }
    __syncthreads();   // O visible; Q/K/VT reads done
    // ---- proj accumulate directly into t: A=Wproj rows=own outch, B=O col=tok ----
    {
      bf16x8 aw[3];
      #pragma unroll
      for(int mt=0;mt<3;++mt) aw[mt]=*(const bf16x8*)(wprojT+(16*(3*w+mt)+l16)*192+h*32+lg*8);
      bf16x8 bo[4];
      #pragma unroll
      for(int tt=0;tt<4;++tt) bo[tt]=*(const bf16x8*)(sm+qp_off(RO_B,16*tt+l16,lg*16));
      #pragma unroll
      for(int mt=0;mt<3;++mt){
        #pragma unroll
        for(int tt=0;tt<4;++tt)
          t[mt][tt]=__builtin_amdgcn_mfma_f32_16x16x32_bf16(aw[mt],bo[tt],t[mt][tt],0,0,0);
      }
    }
    if(h<5){ c1(h+1); __syncthreads(); }
  }

  // ---- proj bias once ----
  #pragma unroll
  for(int mt=0;mt<3;++mt){
    const f32x4 bp=*(const f32x4*)(bproj+48*w+16*mt+4*lg);
    #pragma unroll
    for(int tt=0;tt<4;++tt) t[mt][tt]+=bp;
  }

  // ---- LN2 (red overlays RQ; all Q reads finished) ----
  layernorm(ln2g, ln2b);
  __syncthreads();   // h2 visible; attn buffers dead -> G area free

  // ---- MLP: 12 chunks of 64 mch, double-buffered G (2x8192), 1 barrier/chunk ----
  auto mlp1=[&](int qc){
    char* gbuf = sm + RG_B + (qc&1)*8192;
    bf16x8 aw[6];
    #pragma unroll
    for(int ks=0;ks<6;++ks) aw[ks]=*(const bf16x8*)(wmlp1T+(qc*64+16*w+l16)*192+ks*32+lg*8);
    f32x4 g[4];
    #pragma unroll
    for(int tt=0;tt<4;++tt) g[tt]=(f32x4){0,0,0,0};
    #pragma unroll
    for(int ks=0;ks<6;++ks){
      #pragma unroll
      for(int tt=0;tt<4;++tt){
        const bf16x8 bh2=*(const bf16x8*)(sm+sa_off(16*tt+l16,ks*64+lg*16));
        g[tt]=__builtin_amdgcn_mfma_f32_16x16x32_bf16(aw[ks],bh2,g[tt],0,0,0);
      }
    }
    const f32x4 b1=*(const f32x4*)(bmlp1+qc*64+16*w+4*lg);
    #pragma unroll
    for(int tt=0;tt<4;++tt){
      u16x4 pg;
      #pragma unroll
      for(int r=0;r<4;++r){
        const float xv=g[tt][r]+b1[r];
        const float e=exp2f(-2.4554664f*xv);        // gelu ~ x*sigmoid(1.702x)
        pg[r]=f2b(xv*__builtin_amdgcn_rcpf(1.f+e));
      }
      *(u16x4*)(gbuf+gq_off(16*tt+l16, 32*w+8*lg))=pg;   // G[tok][mch-local]
    }
  };
  auto mlp2=[&](int qc){
    const char* gbuf = sm + RG_B + (qc&1)*8192;
    bf16x8 aw2[2][3];
    #pragma unroll
    for(int ks2=0;ks2<2;++ks2)
      #pragma unroll
      for(int mt=0;mt<3;++mt)
        aw2[ks2][mt]=*(const bf16x8*)(wmlp2T+(16*(3*w+mt)+l16)*768+qc*64+ks2*32+lg*8);
    #pragma unroll
    for(int ks2=0;ks2<2;++ks2){
      bf16x8 bg[4];
      #pragma unroll
      for(int tt=0;tt<4;++tt) bg[tt]=*(const bf16x8*)(gbuf+gq_off(16*tt+l16,ks2*64+lg*16));
      #pragma unroll
      for(int mt=0;mt<3;++mt){
        #pragma unroll
        for(int tt=0;tt<4;++tt)
          t[mt][tt]=__builtin_amdgcn_mfma_f32_16x16x32_bf16(aw2[ks2][mt],bg[tt],t[mt][tt],0,0,0);
      }
    }
  };

  mlp1(0);
  __syncthreads();             // G(0) visible
  #pragma unroll 1
  for(int qc=0;qc<12;++qc){
    mlp2(qc);                  // consume buf[qc&1]
    if(qc<11) mlp1(qc+1);      // produce buf[(qc+1)&1]
    __syncthreads();           // G(qc+1) visible; G(qc) reads done
  }

  // ---- Final: out = t + bmlp2 (regular stores; NT reverted: it tripled FETCH) ----
  #pragma unroll
  for(int mt=0;mt<3;++mt){
    const f32x4 b2=*(const f32x4*)(bmlp2+48*w+16*mt+4*lg);
    #pragma unroll
    for(int tt=0;tt<4;++tt){
      const int T=16*tt+l16, tp=(T>>3)*256+(T&7);
      #pragma unroll
      for(int r=0;r<4;++r)
        outp[imgoff+(size_t)(48*w+16*mt+4*lg+r)*65536+tp]=t[mt][tt][r]+b2[r];
    }
  }
}

extern "C" void kernel_launch(void* const* d_in, const int* in_sizes, int n_in,
                              void* d_out, int out_size, void* d_ws, size_t ws_size,
                              hipStream_t stream) {
  const float* x      = (const float*)d_in[0];
  const float* w_qkv  = (const float*)d_in[1];
  const float* b_qkv  = (const float*)d_in[2];
  const float* w_proj = (const float*)d_in[3];
  const float* b_proj = (const float*)d_in[4];
  const float* ln1g   = (const float*)d_in[5];
  const float* ln1b   = (const float*)d_in[6];
  const float* ln2g   = (const float*)d_in[7];
  const float* ln2b   = (const float*)d_in[8];
  const float* w_mlp1 = (const float*)d_in[9];
  const float* b_mlp1 = (const float*)d_in[10];
  const float* w_mlp2 = (const float*)d_in[11];
  const float* b_mlp2 = (const float*)d_in[12];
  float* out = (float*)d_out;
  unsigned short* wsu = (unsigned short*)d_ws;

  prep_weights<<<dim3(1728), dim3(256), 0, stream>>>(w_qkv, w_proj, w_mlp1, w_mlp2, wsu);
  winblock<<<dim3(4096), dim3(256), 0, stream>>>(
      x, out, b_qkv, b_proj, ln1g, ln1b, ln2g, ln2b, b_mlp1, b_mlp2,
      wsu, wsu+110592, wsu+147456, wsu+294912);
}

// Round 17
// 766.091 us; speedup vs baseline: 1.0489x; 1.0489x over previous
//
#include <hip/hip_runtime.h>
#include <hip/hip_bf16.h>
#include <math.h>

typedef float f32x4 __attribute__((ext_vector_type(4)));
typedef float f32x2 __attribute__((ext_vector_type(2)));
typedef __bf16 bf16x8 __attribute__((ext_vector_type(8)));
typedef unsigned short u16x4 __attribute__((ext_vector_type(4)));

// ---------------- LDS map (40960 B exactly -> 4 blocks/CU) ----------------
// SA 24576 | RQ/RK/RVT/RO 4x4096 | MLP: G double-buffer 2x8192 overlays RQ..RO
#define SA_B  0
#define RQ_B  24576
#define RK_B  28672
#define RVT_B 32768
#define RO_B  36864
#define RG_B  24576
#define SMEM  40960

__device__ __forceinline__ int sa_off(int row,int byte){ return SA_B + row*384 + (byte ^ ((row&7)<<4)); }
__device__ __forceinline__ int vt_off(int row,int byte){ return RVT_B+ row*128 + (byte ^ ((row&7)<<4)); }
__device__ __forceinline__ int gq_off(int row,int byte){ return row*128 + (byte ^ ((row&7)<<4)); }  // G chunk-64: [64 tok][128B]
__device__ __forceinline__ int qp_off(int base,int tok,int byte){
  return base + (tok>>1)*128 + (tok&1)*64 + (byte ^ (((tok>>1)&3)<<4));
}
__device__ __forceinline__ unsigned short f2b(float x){ return __builtin_bit_cast(unsigned short, (__bf16)x); }

union U64 { unsigned long long u; u16x4 v; };
union U128 { unsigned long long q[2]; bf16x8 b; };

// Transpose + cast weights to bf16 [N][K]
__global__ void prep_weights(const float* __restrict__ wqkv, const float* __restrict__ wproj,
                             const float* __restrict__ wmlp1, const float* __restrict__ wmlp2,
                             unsigned short* __restrict__ ws){
  int idx = blockIdx.x*256 + threadIdx.x;
  if (idx < 110592){ int n=idx/192, k=idx%192; ws[idx] = f2b(wqkv[k*576+n]); }
  else if (idx < 147456){ int i=idx-110592; int n=i/192, k=i%192; ws[idx] = f2b(wproj[k*192+n]); }
  else if (idx < 294912){ int i=idx-147456; int n=i/192, k=i%192; ws[idx] = f2b(wmlp1[k*768+n]); }
  else if (idx < 442368){ int i=idx-294912; int n=i/768, k=i%768; ws[idx] = f2b(wmlp2[k*192+n]); }
}

// K2. Thread (w,lg,l16): owns toks {16tt+l16} x chs {48w+16mt+4lg+r}. 40KB LDS, 4 blocks/CU.
__global__ void __launch_bounds__(256, 4) winblock(
    const float* __restrict__ xin, float* __restrict__ outp,
    const float* __restrict__ bqkv, const float* __restrict__ bproj,
    const float* __restrict__ ln1g, const float* __restrict__ ln1b,
    const float* __restrict__ ln2g, const float* __restrict__ ln2b,
    const float* __restrict__ bmlp1, const float* __restrict__ bmlp2,
    const unsigned short* __restrict__ wqkvT, const unsigned short* __restrict__ wprojT,
    const unsigned short* __restrict__ wmlp1T, const unsigned short* __restrict__ wmlp2T)
{
  __shared__ __align__(16) char sm[SMEM];
  const int tid=threadIdx.x, w=tid>>6, lg=(tid>>4)&3, l16=tid&15;
  const int wid=blockIdx.x;
  const int bb=wid>>10, wh=(wid>>5)&31, wwi=wid&31;
  const size_t imgoff=(size_t)bb*192*65536 + (size_t)(wh*8)*256 + (size_t)(wwi*8);
  f32x2* red = (f32x2*)(sm + RQ_B);

  // ---- residual t[mt][tt]: ch 48w+16mt+4lg+r, tok 16tt+l16 ----
  f32x4 t[3][4];
  #pragma unroll
  for(int mt=0;mt<3;++mt)
    #pragma unroll
    for(int tt=0;tt<4;++tt){
      const int T=16*tt+l16, tp=(T>>3)*256+(T&7);
      #pragma unroll
      for(int r=0;r<4;++r)
        t[mt][tt][r]=xin[imgoff+(size_t)(48*w+16*mt+4*lg+r)*65536+tp];
    }

  // ---- LayerNorm -> bf16 into SA (contains one internal barrier) ----
  auto layernorm = [&](const float* gg, const float* bbv){
    float s[4], s2[4];
    #pragma unroll
    for(int tt=0;tt<4;++tt){
      float a=0.f,b2=0.f;
      #pragma unroll
      for(int mt=0;mt<3;++mt){
        #pragma unroll
        for(int r=0;r<4;++r){ a+=t[mt][tt][r]; b2+=t[mt][tt][r]*t[mt][tt][r]; }
      }
      a+=__shfl_xor(a,16); a+=__shfl_xor(a,32);
      b2+=__shfl_xor(b2,16); b2+=__shfl_xor(b2,32);
      s[tt]=a; s2[tt]=b2;
    }
    if(lg==0) red[w*64 +  0+l16]=(f32x2){s[0],s2[0]};
    if(lg==1) red[w*64 + 16+l16]=(f32x2){s[1],s2[1]};
    if(lg==2) red[w*64 + 32+l16]=(f32x2){s[2],s2[2]};
    if(lg==3) red[w*64 + 48+l16]=(f32x2){s[3],s2[3]};
    __syncthreads();
    float mean[4], rstd[4];
    #pragma unroll
    for(int tt=0;tt<4;++tt){
      float S=0.f,S2=0.f;
      #pragma unroll
      for(int w2=0;w2<4;++w2){ f32x2 v=red[w2*64+16*tt+l16]; S+=v.x; S2+=v.y; }
      mean[tt]=S*(1.f/192.f);
      rstd[tt]=rsqrtf(S2*(1.f/192.f)-mean[tt]*mean[tt]+1e-5f);
    }
    #pragma unroll
    for(int mt=0;mt<3;++mt){
      const f32x4 g4=*(const f32x4*)(gg+48*w+16*mt+4*lg);
      const f32x4 b4=*(const f32x4*)(bbv+48*w+16*mt+4*lg);
      #pragma unroll
      for(int tt=0;tt<4;++tt){
        u16x4 pk;
        #pragma unroll
        for(int r=0;r<4;++r) pk[r]=f2b((t[mt][tt][r]-mean[tt])*rstd[tt]*g4[r]+b4[r]);
        *(u16x4*)(sm+sa_off(16*tt+l16,(48*w+16*mt+4*lg)*2))=pk;
      }
    }
  };

  layernorm(ln1g, ln1b);
  __syncthreads();   // h visible

  // ---- QKV producer: wave w -> ct=w>>1 (ch-half of head), tok-tiles {2(w&1),+1} ----
  const int ct=w>>1, tbase=2*(w&1);
  auto c1=[&](int hh){
    f32x4 qa[2],ka[2],va[2];
    #pragma unroll
    for(int i=0;i<2;++i){ qa[i]=(f32x4){0,0,0,0}; ka[i]=(f32x4){0,0,0,0}; va[i]=(f32x4){0,0,0,0}; }
    #pragma unroll
    for(int ks=0;ks<6;++ks){
      bf16x8 hfrag[2];
      #pragma unroll
      for(int i=0;i<2;++i) hfrag[i]=*(const bf16x8*)(sm+sa_off(16*(tbase+i)+l16, ks*64+lg*16));
      const bf16x8 awq=*(const bf16x8*)(wqkvT+(      hh*32+ct*16+l16)*192+ks*32+lg*8);
      const bf16x8 awk=*(const bf16x8*)(wqkvT+(192 + hh*32+ct*16+l16)*192+ks*32+lg*8);
      const bf16x8 bwv=*(const bf16x8*)(wqkvT+(384 + hh*32+ct*16+l16)*192+ks*32+lg*8);
      #pragma unroll
      for(int i=0;i<2;++i){
        qa[i]=__builtin_amdgcn_mfma_f32_16x16x32_bf16(awq,hfrag[i],qa[i],0,0,0);  // D[qch][tok]
        ka[i]=__builtin_amdgcn_mfma_f32_16x16x32_bf16(awk,hfrag[i],ka[i],0,0,0);
        va[i]=__builtin_amdgcn_mfma_f32_16x16x32_bf16(hfrag[i],bwv,va[i],0,0,0);  // D[tok][vch]
      }
    }
    const f32x4 bq4=*(const f32x4*)(bqkv+      hh*32+ct*16+4*lg);
    const f32x4 bk4=*(const f32x4*)(bqkv+192 + hh*32+ct*16+4*lg);
    const float bv =bqkv[384 + hh*32+ct*16+l16];
    #pragma unroll
    for(int i=0;i<2;++i){
      const int tok=16*(tbase+i)+l16;
      u16x4 pq,pk,pv;
      #pragma unroll
      for(int r=0;r<4;++r){
        pq[r]=f2b(qa[i][r]+bq4[r]);
        pk[r]=f2b(ka[i][r]+bk4[r]);
        pv[r]=f2b(va[i][r]+bv);
      }
      *(u16x4*)(sm+qp_off(RQ_B,tok,32*ct+8*lg))=pq;                  // Q[tok][qch]
      *(u16x4*)(sm+qp_off(RK_B,tok,32*ct+8*lg))=pk;                  // K[tok][qch]
      *(u16x4*)(sm+vt_off(ct*16+l16,(16*(tbase+i)+4*lg)*2))=pv;      // VT[vch][tok]
    }
  };

  c1(0);
  __syncthreads();

  const float SM_C = 0.25503487f;  // log2(e)/sqrt(32), applied in f32 at exp2
  #pragma unroll 1
  for(int h=0;h<6;++h){
    // ---- S^T = K.Q (A=K rows=ktok, B=Q col=own q) ; softmax in-register ----
    {
      const int q=16*w+l16;
      const bf16x8 bqf=*(const bf16x8*)(sm+qp_off(RQ_B,q,lg*16));
      f32x4 sv[4];
      #pragma unroll
      for(int kt=0;kt<4;++kt){
        const bf16x8 akf=*(const bf16x8*)(sm+qp_off(RK_B,16*kt+l16,lg*16));
        sv[kt]=__builtin_amdgcn_mfma_f32_16x16x32_bf16(akf,bqf,(f32x4){0,0,0,0},0,0,0);
      }
      float mx=-3.0e38f;
      #pragma unroll
      for(int kt=0;kt<4;++kt){
        #pragma unroll
        for(int r=0;r<4;++r) mx=fmaxf(mx,sv[kt][r]);
      }
      mx=fmaxf(mx,__shfl_xor(mx,16)); mx=fmaxf(mx,__shfl_xor(mx,32));
      float sum=0.f;
      #pragma unroll
      for(int kt=0;kt<4;++kt){
        #pragma unroll
        for(int r=0;r<4;++r){ float e=exp2f((sv[kt][r]-mx)*SM_C); sv[kt][r]=e; sum+=e; }
      }
      sum+=__shfl_xor(sum,16); sum+=__shfl_xor(sum,32);
      const float rs=1.f/sum;
      U64 pk0,pk1,pk2,pk3;
      #pragma unroll
      for(int r=0;r<4;++r){ pk0.v[r]=f2b(sv[0][r]*rs); pk1.v[r]=f2b(sv[1][r]*rs);
                            pk2.v[r]=f2b(sv[2][r]*rs); pk3.v[r]=f2b(sv[3][r]*rs); }
      const int srcA = ((lg&1)<<5) + l16, srcB = srcA + 16;
      unsigned long long rA0=__shfl(pk0.u,srcA), rB0=__shfl(pk0.u,srcB);
      unsigned long long rA1=__shfl(pk1.u,srcA), rB1=__shfl(pk1.u,srcB);
      unsigned long long rA2=__shfl(pk2.u,srcA), rB2=__shfl(pk2.u,srcB);
      unsigned long long rA3=__shfl(pk3.u,srcA), rB3=__shfl(pk3.u,srcB);
      U128 pf0, pf1;
      pf0.q[0]=(lg<2)?rA0:rA1;  pf0.q[1]=(lg<2)?rB0:rB1;   // ktok 0..31
      pf1.q[0]=(lg<2)?rA2:rA3;  pf1.q[1]=(lg<2)?rB2:rB3;   // ktok 32..63
      // ---- PV: A=VT (rows d), B=P (col=own q) -> D[d][q]; write O[q][d] ----
      f32x4 ov[2]={(f32x4){0,0,0,0},(f32x4){0,0,0,0}};
      #pragma unroll
      for(int dt=0;dt<2;++dt){
        const bf16x8 av0=*(const bf16x8*)(sm+vt_off(16*dt+l16,lg*16));
        const bf16x8 av1=*(const bf16x8*)(sm+vt_off(16*dt+l16,64+lg*16));
        ov[dt]=__builtin_amdgcn_mfma_f32_16x16x32_bf16(av0,pf0.b,ov[dt],0,0,0);
        ov[dt]=__builtin_amdgcn_mfma_f32_16x16x32_bf16(av1,pf1.b,ov[dt],0,0,0);
      }
      #pragma unroll
      for(int dt=0;dt<2;++dt){
        u16x4 po;
        #pragma unroll
        for(int r=0;r<4;++r) po[r]=f2b(ov[dt][r]);
        *(u16x4*)(sm+qp_off(RO_B,q,32*dt+8*lg))=po;   // own q row
      }
    }
    __syncthreads();   // O visible; Q/K/VT reads done
    // ---- proj accumulate directly into t: A=Wproj rows=own outch, B=O col=tok ----
    {
      bf16x8 bo[4];
      #pragma unroll
      for(int tt=0;tt<4;++tt) bo[tt]=*(const bf16x8*)(sm+qp_off(RO_B,16*tt+l16,lg*16));
      #pragma unroll
      for(int mt=0;mt<3;++mt){
        const bf16x8 aw=*(const bf16x8*)(wprojT+(16*(3*w+mt)+l16)*192+h*32+lg*8);
        #pragma unroll
        for(int tt=0;tt<4;++tt)
          t[mt][tt]=__builtin_amdgcn_mfma_f32_16x16x32_bf16(aw,bo[tt],t[mt][tt],0,0,0);
      }
    }
    if(h<5){ c1(h+1); __syncthreads(); }
  }

  // ---- proj bias once ----
  #pragma unroll
  for(int mt=0;mt<3;++mt){
    const f32x4 bp=*(const f32x4*)(bproj+48*w+16*mt+4*lg);
    #pragma unroll
    for(int tt=0;tt<4;++tt) t[mt][tt]+=bp;
  }

  // ---- LN2 (red overlays RQ; all Q reads finished) ----
  layernorm(ln2g, ln2b);
  __syncthreads();   // h2 visible; attn buffers dead -> G area free

  // ---- MLP: 12 chunks of 64 mch, double-buffered G (2x8192), 1 barrier/chunk ----
  auto mlp1=[&](int qc){
    char* gbuf = sm + RG_B + (qc&1)*8192;
    f32x4 g[4];
    #pragma unroll
    for(int tt=0;tt<4;++tt) g[tt]=(f32x4){0,0,0,0};
    #pragma unroll
    for(int ks=0;ks<6;++ks){
      const bf16x8 aw=*(const bf16x8*)(wmlp1T+(qc*64+16*w+l16)*192+ks*32+lg*8);
      #pragma unroll
      for(int tt=0;tt<4;++tt){
        const bf16x8 bh2=*(const bf16x8*)(sm+sa_off(16*tt+l16,ks*64+lg*16));
        g[tt]=__builtin_amdgcn_mfma_f32_16x16x32_bf16(aw,bh2,g[tt],0,0,0);
      }
    }
    const f32x4 b1=*(const f32x4*)(bmlp1+qc*64+16*w+4*lg);
    #pragma unroll
    for(int tt=0;tt<4;++tt){
      u16x4 pg;
      #pragma unroll
      for(int r=0;r<4;++r){
        const float xv=g[tt][r]+b1[r];
        const float e=exp2f(-2.4554664f*xv);        // gelu ~ x*sigmoid(1.702x)
        pg[r]=f2b(xv*__builtin_amdgcn_rcpf(1.f+e));
      }
      *(u16x4*)(gbuf+gq_off(16*tt+l16, 32*w+8*lg))=pg;   // G[tok][mch-local]
    }
  };
  auto mlp2=[&](int qc){
    const char* gbuf = sm + RG_B + (qc&1)*8192;
    #pragma unroll
    for(int ks2=0;ks2<2;++ks2){
      bf16x8 bg[4];
      #pragma unroll
      for(int tt=0;tt<4;++tt) bg[tt]=*(const bf16x8*)(gbuf+gq_off(16*tt+l16,ks2*64+lg*16));
      #pragma unroll
      for(int mt=0;mt<3;++mt){
        const bf16x8 aw2=*(const bf16x8*)(wmlp2T+(16*(3*w+mt)+l16)*768+qc*64+ks2*32+lg*8);
        #pragma unroll
        for(int tt=0;tt<4;++tt)
          t[mt][tt]=__builtin_amdgcn_mfma_f32_16x16x32_bf16(aw2,bg[tt],t[mt][tt],0,0,0);
      }
    }
  };

  mlp1(0);
  __syncthreads();             // G(0) visible
  #pragma unroll 1
  for(int qc=0;qc<12;++qc){
    mlp2(qc);                  // consume buf[qc&1]
    if(qc<11) mlp1(qc+1);      // produce buf[(qc+1)&1]
    __syncthreads();           // G(qc+1) visible; G(qc) reads done
  }

  // ---- Final: out = t + bmlp2 (regular stores) ----
  #pragma unroll
  for(int mt=0;mt<3;++mt){
    const f32x4 b2=*(const f32x4*)(bmlp2+48*w+16*mt+4*lg);
    #pragma unroll
    for(int tt=0;tt<4;++tt){
      const int T=16*tt+l16, tp=(T>>3)*256+(T&7);
      #pragma unroll
      for(int r=0;r<4;++r)
        outp[imgoff+(size_t)(48*w+16*mt+4*lg+r)*65536+tp]=t[mt][tt][r]+b2[r];
    }
  }
}

extern "C" void kernel_launch(void* const* d_in, const int* in_sizes, int n_in,
                              void* d_out, int out_size, void* d_ws, size_t ws_size,
                              hipStream_t stream) {
  const float* x      = (const float*)d_in[0];
  const float* w_qkv  = (const float*)d_in[1];
  const float* b_qkv  = (const float*)d_in[2];
  const float* w_proj = (const float*)d_in[3];
  const float* b_proj = (const float*)d_in[4];
  const float* ln1g   = (const float*)d_in[5];
  const float* ln1b   = (const float*)d_in[6];
  const float* ln2g   = (const float*)d_in[7];
  const float* ln2b   = (const float*)d_in[8];
  const float* w_mlp1 = (const float*)d_in[9];
  const float* b_mlp1 = (const float*)d_in[10];
  const float* w_mlp2 = (const float*)d_in[11];
  const float* b_mlp2 = (const float*)d_in[12];
  float* out = (float*)d_out;
  unsigned short* wsu = (unsigned short*)d_ws;

  prep_weights<<<dim3(1728), dim3(256), 0, stream>>>(w_qkv, w_proj, w_mlp1, w_mlp2, wsu);
  winblock<<<dim3(4096), dim3(256), 0, stream>>>(
      x, out, b_qkv, b_proj, ln1g, ln1b, ln2g, ln2b, b_mlp1, b_mlp2,
      wsu, wsu+110592, wsu+147456, wsu+294912);
}

// Round 18
// 735.268 us; speedup vs baseline: 1.0929x; 1.0419x over previous
//
#include <hip/hip_runtime.h>
#include <hip/hip_bf16.h>
#include <math.h>

typedef float f32x4 __attribute__((ext_vector_type(4)));
typedef float f32x2 __attribute__((ext_vector_type(2)));
typedef __bf16 bf16x8 __attribute__((ext_vector_type(8)));
typedef unsigned short u16x4 __attribute__((ext_vector_type(4)));

// ---------------- LDS map (40960 B exactly -> 4 blocks/CU) ----------------
// SA 24576 | RQ/RK/RVT/RO 4x4096 | MLP: G double-buffer 2x8192 overlays RQ..RO
#define SA_B  0
#define RQ_B  24576
#define RK_B  28672
#define RVT_B 32768
#define RO_B  36864
#define RG_B  24576
#define SMEM  40960

__device__ __forceinline__ int sa_off(int row,int byte){ return SA_B + row*384 + (byte ^ ((row&7)<<4)); }
__device__ __forceinline__ int vt_off(int row,int byte){ return RVT_B+ row*128 + (byte ^ ((row&7)<<4)); }
__device__ __forceinline__ int gq_off(int row,int byte){ return row*128 + (byte ^ ((row&7)<<4)); }  // G chunk-64: [64 tok][128B]
__device__ __forceinline__ int qp_off(int base,int tok,int byte){
  return base + (tok>>1)*128 + (tok&1)*64 + (byte ^ (((tok>>1)&3)<<4));
}
__device__ __forceinline__ unsigned short f2b(float x){ return __builtin_bit_cast(unsigned short, (__bf16)x); }

union U64 { unsigned long long u; u16x4 v; };
union U128 { unsigned long long q[2]; bf16x8 b; };

// Transpose + cast weights to bf16 [N][K]
__global__ void prep_weights(const float* __restrict__ wqkv, const float* __restrict__ wproj,
                             const float* __restrict__ wmlp1, const float* __restrict__ wmlp2,
                             unsigned short* __restrict__ ws){
  int idx = blockIdx.x*256 + threadIdx.x;
  if (idx < 110592){ int n=idx/192, k=idx%192; ws[idx] = f2b(wqkv[k*576+n]); }
  else if (idx < 147456){ int i=idx-110592; int n=i/192, k=i%192; ws[idx] = f2b(wproj[k*192+n]); }
  else if (idx < 294912){ int i=idx-147456; int n=i/192, k=i%192; ws[idx] = f2b(wmlp1[k*768+n]); }
  else if (idx < 442368){ int i=idx-294912; int n=i/768, k=i%768; ws[idx] = f2b(wmlp2[k*192+n]); }
}

// K2. Thread (w,lg,l16): owns toks {16tt+l16} x chs {48w+16mt+4lg+r}. 40KB LDS, 4 blocks/CU.
// launch_bounds min-waves 4 -> 2: LDS already caps occupancy at 4 blocks/CU, but the lower
// bound frees the allocator to use >64 VGPRs for batched weight fragments (R16 spilled at 64).
__global__ void __launch_bounds__(256, 2) winblock(
    const float* __restrict__ xin, float* __restrict__ outp,
    const float* __restrict__ bqkv, const float* __restrict__ bproj,
    const float* __restrict__ ln1g, const float* __restrict__ ln1b,
    const float* __restrict__ ln2g, const float* __restrict__ ln2b,
    const float* __restrict__ bmlp1, const float* __restrict__ bmlp2,
    const unsigned short* __restrict__ wqkvT, const unsigned short* __restrict__ wprojT,
    const unsigned short* __restrict__ wmlp1T, const unsigned short* __restrict__ wmlp2T)
{
  __shared__ __align__(16) char sm[SMEM];
  const int tid=threadIdx.x, w=tid>>6, lg=(tid>>4)&3, l16=tid&15;
  const int wid=blockIdx.x;
  const int bb=wid>>10, wh=(wid>>5)&31, wwi=wid&31;
  const size_t imgoff=(size_t)bb*192*65536 + (size_t)(wh*8)*256 + (size_t)(wwi*8);
  f32x2* red = (f32x2*)(sm + RQ_B);

  // ---- residual t[mt][tt]: ch 48w+16mt+4lg+r, tok 16tt+l16 ----
  f32x4 t[3][4];
  #pragma unroll
  for(int mt=0;mt<3;++mt)
    #pragma unroll
    for(int tt=0;tt<4;++tt){
      const int T=16*tt+l16, tp=(T>>3)*256+(T&7);
      #pragma unroll
      for(int r=0;r<4;++r)
        t[mt][tt][r]=xin[imgoff+(size_t)(48*w+16*mt+4*lg+r)*65536+tp];
    }

  // ---- LayerNorm -> bf16 into SA (contains one internal barrier) ----
  auto layernorm = [&](const float* gg, const float* bbv){
    float s[4], s2[4];
    #pragma unroll
    for(int tt=0;tt<4;++tt){
      float a=0.f,b2=0.f;
      #pragma unroll
      for(int mt=0;mt<3;++mt){
        #pragma unroll
        for(int r=0;r<4;++r){ a+=t[mt][tt][r]; b2+=t[mt][tt][r]*t[mt][tt][r]; }
      }
      a+=__shfl_xor(a,16); a+=__shfl_xor(a,32);
      b2+=__shfl_xor(b2,16); b2+=__shfl_xor(b2,32);
      s[tt]=a; s2[tt]=b2;
    }
    if(lg==0) red[w*64 +  0+l16]=(f32x2){s[0],s2[0]};
    if(lg==1) red[w*64 + 16+l16]=(f32x2){s[1],s2[1]};
    if(lg==2) red[w*64 + 32+l16]=(f32x2){s[2],s2[2]};
    if(lg==3) red[w*64 + 48+l16]=(f32x2){s[3],s2[3]};
    __syncthreads();
    float mean[4], rstd[4];
    #pragma unroll
    for(int tt=0;tt<4;++tt){
      float S=0.f,S2=0.f;
      #pragma unroll
      for(int w2=0;w2<4;++w2){ f32x2 v=red[w2*64+16*tt+l16]; S+=v.x; S2+=v.y; }
      mean[tt]=S*(1.f/192.f);
      rstd[tt]=rsqrtf(S2*(1.f/192.f)-mean[tt]*mean[tt]+1e-5f);
    }
    #pragma unroll
    for(int mt=0;mt<3;++mt){
      const f32x4 g4=*(const f32x4*)(gg+48*w+16*mt+4*lg);
      const f32x4 b4=*(const f32x4*)(bbv+48*w+16*mt+4*lg);
      #pragma unroll
      for(int tt=0;tt<4;++tt){
        u16x4 pk;
        #pragma unroll
        for(int r=0;r<4;++r) pk[r]=f2b((t[mt][tt][r]-mean[tt])*rstd[tt]*g4[r]+b4[r]);
        *(u16x4*)(sm+sa_off(16*tt+l16,(48*w+16*mt+4*lg)*2))=pk;
      }
    }
  };

  layernorm(ln1g, ln1b);
  __syncthreads();   // h visible

  // ---- QKV producer: wave w -> ct=w>>1 (ch-half of head), tok-tiles {2(w&1),+1} ----
  // Weight fragments batched 9-at-a-time (3 ks) to keep loads in flight.
  const int ct=w>>1, tbase=2*(w&1);
  auto c1=[&](int hh){
    f32x4 qa[2],ka[2],va[2];
    #pragma unroll
    for(int i=0;i<2;++i){ qa[i]=(f32x4){0,0,0,0}; ka[i]=(f32x4){0,0,0,0}; va[i]=(f32x4){0,0,0,0}; }
    #pragma unroll
    for(int hf=0;hf<2;++hf){
      bf16x8 wq[3],wk[3],wv[3];
      #pragma unroll
      for(int k3=0;k3<3;++k3){
        const int ks=hf*3+k3;
        wq[k3]=*(const bf16x8*)(wqkvT+(      hh*32+ct*16+l16)*192+ks*32+lg*8);
        wk[k3]=*(const bf16x8*)(wqkvT+(192 + hh*32+ct*16+l16)*192+ks*32+lg*8);
        wv[k3]=*(const bf16x8*)(wqkvT+(384 + hh*32+ct*16+l16)*192+ks*32+lg*8);
      }
      #pragma unroll
      for(int k3=0;k3<3;++k3){
        const int ks=hf*3+k3;
        bf16x8 hfrag[2];
        #pragma unroll
        for(int i=0;i<2;++i) hfrag[i]=*(const bf16x8*)(sm+sa_off(16*(tbase+i)+l16, ks*64+lg*16));
        #pragma unroll
        for(int i=0;i<2;++i){
          qa[i]=__builtin_amdgcn_mfma_f32_16x16x32_bf16(wq[k3],hfrag[i],qa[i],0,0,0);  // D[qch][tok]
          ka[i]=__builtin_amdgcn_mfma_f32_16x16x32_bf16(wk[k3],hfrag[i],ka[i],0,0,0);
          va[i]=__builtin_amdgcn_mfma_f32_16x16x32_bf16(hfrag[i],wv[k3],va[i],0,0,0);  // D[tok][vch]
        }
      }
    }
    const f32x4 bq4=*(const f32x4*)(bqkv+      hh*32+ct*16+4*lg);
    const f32x4 bk4=*(const f32x4*)(bqkv+192 + hh*32+ct*16+4*lg);
    const float bv =bqkv[384 + hh*32+ct*16+l16];
    #pragma unroll
    for(int i=0;i<2;++i){
      const int tok=16*(tbase+i)+l16;
      u16x4 pq,pk,pv;
      #pragma unroll
      for(int r=0;r<4;++r){
        pq[r]=f2b(qa[i][r]+bq4[r]);
        pk[r]=f2b(ka[i][r]+bk4[r]);
        pv[r]=f2b(va[i][r]+bv);
      }
      *(u16x4*)(sm+qp_off(RQ_B,tok,32*ct+8*lg))=pq;                  // Q[tok][qch]
      *(u16x4*)(sm+qp_off(RK_B,tok,32*ct+8*lg))=pk;                  // K[tok][qch]
      *(u16x4*)(sm+vt_off(ct*16+l16,(16*(tbase+i)+4*lg)*2))=pv;      // VT[vch][tok]
    }
  };

  c1(0);
  __syncthreads();

  const float SM_C = 0.25503487f;  // log2(e)/sqrt(32), applied in f32 at exp2
  #pragma unroll 1
  for(int h=0;h<6;++h){
    // ---- S^T = K.Q (A=K rows=ktok, B=Q col=own q) ; softmax in-register ----
    {
      const int q=16*w+l16;
      const bf16x8 bqf=*(const bf16x8*)(sm+qp_off(RQ_B,q,lg*16));
      f32x4 sv[4];
      #pragma unroll
      for(int kt=0;kt<4;++kt){
        const bf16x8 akf=*(const bf16x8*)(sm+qp_off(RK_B,16*kt+l16,lg*16));
        sv[kt]=__builtin_amdgcn_mfma_f32_16x16x32_bf16(akf,bqf,(f32x4){0,0,0,0},0,0,0);
      }
      float mx=-3.0e38f;
      #pragma unroll
      for(int kt=0;kt<4;++kt){
        #pragma unroll
        for(int r=0;r<4;++r) mx=fmaxf(mx,sv[kt][r]);
      }
      mx=fmaxf(mx,__shfl_xor(mx,16)); mx=fmaxf(mx,__shfl_xor(mx,32));
      float sum=0.f;
      #pragma unroll
      for(int kt=0;kt<4;++kt){
        #pragma unroll
        for(int r=0;r<4;++r){ float e=exp2f((sv[kt][r]-mx)*SM_C); sv[kt][r]=e; sum+=e; }
      }
      sum+=__shfl_xor(sum,16); sum+=__shfl_xor(sum,32);
      const float rs=1.f/sum;
      U64 pk0,pk1,pk2,pk3;
      #pragma unroll
      for(int r=0;r<4;++r){ pk0.v[r]=f2b(sv[0][r]*rs); pk1.v[r]=f2b(sv[1][r]*rs);
                            pk2.v[r]=f2b(sv[2][r]*rs); pk3.v[r]=f2b(sv[3][r]*rs); }
      const int srcA = ((lg&1)<<5) + l16, srcB = srcA + 16;
      unsigned long long rA0=__shfl(pk0.u,srcA), rB0=__shfl(pk0.u,srcB);
      unsigned long long rA1=__shfl(pk1.u,srcA), rB1=__shfl(pk1.u,srcB);
      unsigned long long rA2=__shfl(pk2.u,srcA), rB2=__shfl(pk2.u,srcB);
      unsigned long long rA3=__shfl(pk3.u,srcA), rB3=__shfl(pk3.u,srcB);
      U128 pf0, pf1;
      pf0.q[0]=(lg<2)?rA0:rA1;  pf0.q[1]=(lg<2)?rB0:rB1;   // ktok 0..31
      pf1.q[0]=(lg<2)?rA2:rA3;  pf1.q[1]=(lg<2)?rB2:rB3;   // ktok 32..63
      // ---- PV: A=VT (rows d), B=P (col=own q) -> D[d][q]; write O[q][d] ----
      f32x4 ov[2]={(f32x4){0,0,0,0},(f32x4){0,0,0,0}};
      #pragma unroll
      for(int dt=0;dt<2;++dt){
        const bf16x8 av0=*(const bf16x8*)(sm+vt_off(16*dt+l16,lg*16));
        const bf16x8 av1=*(const bf16x8*)(sm+vt_off(16*dt+l16,64+lg*16));
        ov[dt]=__builtin_amdgcn_mfma_f32_16x16x32_bf16(av0,pf0.b,ov[dt],0,0,0);
        ov[dt]=__builtin_amdgcn_mfma_f32_16x16x32_bf16(av1,pf1.b,ov[dt],0,0,0);
      }
      #pragma unroll
      for(int dt=0;dt<2;++dt){
        u16x4 po;
        #pragma unroll
        for(int r=0;r<4;++r) po[r]=f2b(ov[dt][r]);
        *(u16x4*)(sm+qp_off(RO_B,q,32*dt+8*lg))=po;   // own q row
      }
    }
    __syncthreads();   // O visible; Q/K/VT reads done
    // ---- proj accumulate directly into t: A=Wproj rows=own outch, B=O col=tok ----
    {
      bf16x8 aw[3];
      #pragma unroll
      for(int mt=0;mt<3;++mt) aw[mt]=*(const bf16x8*)(wprojT+(16*(3*w+mt)+l16)*192+h*32+lg*8);
      bf16x8 bo[4];
      #pragma unroll
      for(int tt=0;tt<4;++tt) bo[tt]=*(const bf16x8*)(sm+qp_off(RO_B,16*tt+l16,lg*16));
      #pragma unroll
      for(int mt=0;mt<3;++mt){
        #pragma unroll
        for(int tt=0;tt<4;++tt)
          t[mt][tt]=__builtin_amdgcn_mfma_f32_16x16x32_bf16(aw[mt],bo[tt],t[mt][tt],0,0,0);
      }
    }
    if(h<5){ c1(h+1); __syncthreads(); }
  }

  // ---- proj bias once ----
  #pragma unroll
  for(int mt=0;mt<3;++mt){
    const f32x4 bp=*(const f32x4*)(bproj+48*w+16*mt+4*lg);
    #pragma unroll
    for(int tt=0;tt<4;++tt) t[mt][tt]+=bp;
  }

  // ---- LN2 (red overlays RQ; all Q reads finished) ----
  layernorm(ln2g, ln2b);
  __syncthreads();   // h2 visible; attn buffers dead -> G area free

  // ---- MLP: 12 chunks of 64 mch, double-buffered G (2x8192), 1 barrier/chunk ----
  auto mlp1=[&](int qc){
    char* gbuf = sm + RG_B + (qc&1)*8192;
    bf16x8 aw[6];
    #pragma unroll
    for(int ks=0;ks<6;++ks) aw[ks]=*(const bf16x8*)(wmlp1T+(qc*64+16*w+l16)*192+ks*32+lg*8);
    f32x4 g[4];
    #pragma unroll
    for(int tt=0;tt<4;++tt) g[tt]=(f32x4){0,0,0,0};
    #pragma unroll
    for(int ks=0;ks<6;++ks){
      #pragma unroll
      for(int tt=0;tt<4;++tt){
        const bf16x8 bh2=*(const bf16x8*)(sm+sa_off(16*tt+l16,ks*64+lg*16));
        g[tt]=__builtin_amdgcn_mfma_f32_16x16x32_bf16(aw[ks],bh2,g[tt],0,0,0);
      }
    }
    const f32x4 b1=*(const f32x4*)(bmlp1+qc*64+16*w+4*lg);
    #pragma unroll
    for(int tt=0;tt<4;++tt){
      u16x4 pg;
      #pragma unroll
      for(int r=0;r<4;++r){
        const float xv=g[tt][r]+b1[r];
        const float e=exp2f(-2.4554664f*xv);        // gelu ~ x*sigmoid(1.702x)
        pg[r]=f2b(xv*__builtin_amdgcn_rcpf(1.f+e));
      }
      *(u16x4*)(gbuf+gq_off(16*tt+l16, 32*w+8*lg))=pg;   // G[tok][mch-local]
    }
  };
  auto mlp2=[&](int qc){
    const char* gbuf = sm + RG_B + (qc&1)*8192;
    bf16x8 aw2[2][3];
    #pragma unroll
    for(int ks2=0;ks2<2;++ks2)
      #pragma unroll
      for(int mt=0;mt<3;++mt)
        aw2[ks2][mt]=*(const bf16x8*)(wmlp2T+(16*(3*w+mt)+l16)*768+qc*64+ks2*32+lg*8);
    #pragma unroll
    for(int ks2=0;ks2<2;++ks2){
      bf16x8 bg[4];
      #pragma unroll
      for(int tt=0;tt<4;++tt) bg[tt]=*(const bf16x8*)(gbuf+gq_off(16*tt+l16,ks2*64+lg*16));
      #pragma unroll
      for(int mt=0;mt<3;++mt){
        #pragma unroll
        for(int tt=0;tt<4;++tt)
          t[mt][tt]=__builtin_amdgcn_mfma_f32_16x16x32_bf16(aw2[ks2][mt],bg[tt],t[mt][tt],0,0,0);
      }
    }
  };

  mlp1(0);
  __syncthreads();             // G(0) visible
  #pragma unroll 1
  for(int qc=0;qc<12;++qc){
    mlp2(qc);                  // consume buf[qc&1]
    if(qc<11) mlp1(qc+1);      // produce buf[(qc+1)&1]
    __syncthreads();           // G(qc+1) visible; G(qc) reads done
  }

  // ---- Final: out = t + bmlp2 (regular stores) ----
  #pragma unroll
  for(int mt=0;mt<3;++mt){
    const f32x4 b2=*(const f32x4*)(bmlp2+48*w+16*mt+4*lg);
    #pragma unroll
    for(int tt=0;tt<4;++tt){
      const int T=16*tt+l16, tp=(T>>3)*256+(T&7);
      #pragma unroll
      for(int r=0;r<4;++r)
        outp[imgoff+(size_t)(48*w+16*mt+4*lg+r)*65536+tp]=t[mt][tt][r]+b2[r];
    }
  }
}

extern "C" void kernel_launch(void* const* d_in, const int* in_sizes, int n_in,
                              void* d_out, int out_size, void* d_ws, size_t ws_size,
                              hipStream_t stream) {
  const float* x      = (const float*)d_in[0];
  const float* w_qkv  = (const float*)d_in[1];
  const float* b_qkv  = (const float*)d_in[2];
  const float* w_proj = (const float*)d_in[3];
  const float* b_proj = (const float*)d_in[4];
  const float* ln1g   = (const float*)d_in[5];
  const float* ln1b   = (const float*)d_in[6];
  const float* ln2g   = (const float*)d_in[7];
  const float* ln2b   = (const float*)d_in[8];
  const float* w_mlp1 = (const float*)d_in[9];
  const float* b_mlp1 = (const float*)d_in[10];
  const float* w_mlp2 = (const float*)d_in[11];
  const float* b_mlp2 = (const float*)d_in[12];
  float* out = (float*)d_out;
  unsigned short* wsu = (unsigned short*)d_ws;

  prep_weights<<<dim3(1728), dim3(256), 0, stream>>>(w_qkv, w_proj, w_mlp1, w_mlp2, wsu);
  winblock<<<dim3(4096), dim3(256), 0, stream>>>(
      x, out, b_qkv, b_proj, ln1g, ln1b, ln2g, ln2b, b_mlp1, b_mlp2,
      wsu, wsu+110592, wsu+147456, wsu+294912);
}

// Round 19
// 684.908 us; speedup vs baseline: 1.1732x; 1.0735x over previous
//
#include <hip/hip_runtime.h>
#include <hip/hip_bf16.h>
#include <math.h>

typedef float f32x4 __attribute__((ext_vector_type(4)));
typedef float f32x2 __attribute__((ext_vector_type(2)));
typedef __bf16 bf16x8 __attribute__((ext_vector_type(8)));
typedef unsigned short u16x4 __attribute__((ext_vector_type(4)));

// ---------------- LDS map (40960 B exactly) ----------------
// SA 24576 | RQ/RK/RVT/RO 4x4096 | MLP: G double-buffer 2x8192 overlays RQ..RO
#define SA_B  0
#define RQ_B  24576
#define RK_B  28672
#define RVT_B 32768
#define RO_B  36864
#define RG_B  24576
#define SMEM  40960

__device__ __forceinline__ int sa_off(int row,int byte){ return SA_B + row*384 + (byte ^ ((row&7)<<4)); }
__device__ __forceinline__ int vt_off(int row,int byte){ return RVT_B+ row*128 + (byte ^ ((row&7)<<4)); }
__device__ __forceinline__ int gq_off(int row,int byte){ return row*128 + (byte ^ ((row&7)<<4)); }  // G chunk-64: [64 tok][128B]
__device__ __forceinline__ int qp_off(int base,int tok,int byte){
  return base + (tok>>1)*128 + (tok&1)*64 + (byte ^ (((tok>>1)&3)<<4));
}
__device__ __forceinline__ unsigned short f2b(float x){ return __builtin_bit_cast(unsigned short, (__bf16)x); }

union U64 { unsigned long long u; u16x4 v; };
union U128 { unsigned long long q[2]; bf16x8 b; };

// Transpose + cast weights to bf16 [N][K]
__global__ void prep_weights(const float* __restrict__ wqkv, const float* __restrict__ wproj,
                             const float* __restrict__ wmlp1, const float* __restrict__ wmlp2,
                             unsigned short* __restrict__ ws){
  int idx = blockIdx.x*256 + threadIdx.x;
  if (idx < 110592){ int n=idx/192, k=idx%192; ws[idx] = f2b(wqkv[k*576+n]); }
  else if (idx < 147456){ int i=idx-110592; int n=i/192, k=i%192; ws[idx] = f2b(wproj[k*192+n]); }
  else if (idx < 294912){ int i=idx-147456; int n=i/192, k=i%192; ws[idx] = f2b(wmlp1[k*768+n]); }
  else if (idx < 442368){ int i=idx-294912; int n=i/768, k=i%768; ws[idx] = f2b(wmlp2[k*192+n]); }
}

// K2. Thread (w,lg,l16): owns toks {16tt+l16} x chs {48w+16mt+4lg+r}. 40KB LDS.
// launch_bounds(256,3): 3 waves/EU target -> ~170 unified regs (104 arch + 64 acc fits),
// 12 waves/CU vs R18's 8 at the same batched-ILP codegen.
__global__ void __launch_bounds__(256, 3) winblock(
    const float* __restrict__ xin, float* __restrict__ outp,
    const float* __restrict__ bqkv, const float* __restrict__ bproj,
    const float* __restrict__ ln1g, const float* __restrict__ ln1b,
    const float* __restrict__ ln2g, const float* __restrict__ ln2b,
    const float* __restrict__ bmlp1, const float* __restrict__ bmlp2,
    const unsigned short* __restrict__ wqkvT, const unsigned short* __restrict__ wprojT,
    const unsigned short* __restrict__ wmlp1T, const unsigned short* __restrict__ wmlp2T)
{
  __shared__ __align__(16) char sm[SMEM];
  const int tid=threadIdx.x, w=tid>>6, lg=(tid>>4)&3, l16=tid&15;
  const int wid=blockIdx.x;
  const int bb=wid>>10, wh=(wid>>5)&31, wwi=wid&31;
  const size_t imgoff=(size_t)bb*192*65536 + (size_t)(wh*8)*256 + (size_t)(wwi*8);
  f32x2* red = (f32x2*)(sm + RQ_B);

  // ---- residual t[mt][tt]: ch 48w+16mt+4lg+r, tok 16tt+l16 ----
  f32x4 t[3][4];
  #pragma unroll
  for(int mt=0;mt<3;++mt)
    #pragma unroll
    for(int tt=0;tt<4;++tt){
      const int T=16*tt+l16, tp=(T>>3)*256+(T&7);
      #pragma unroll
      for(int r=0;r<4;++r)
        t[mt][tt][r]=xin[imgoff+(size_t)(48*w+16*mt+4*lg+r)*65536+tp];
    }

  // ---- LayerNorm -> bf16 into SA (contains one internal barrier) ----
  auto layernorm = [&](const float* gg, const float* bbv){
    float s[4], s2[4];
    #pragma unroll
    for(int tt=0;tt<4;++tt){
      float a=0.f,b2=0.f;
      #pragma unroll
      for(int mt=0;mt<3;++mt){
        #pragma unroll
        for(int r=0;r<4;++r){ a+=t[mt][tt][r]; b2+=t[mt][tt][r]*t[mt][tt][r]; }
      }
      a+=__shfl_xor(a,16); a+=__shfl_xor(a,32);
      b2+=__shfl_xor(b2,16); b2+=__shfl_xor(b2,32);
      s[tt]=a; s2[tt]=b2;
    }
    if(lg==0) red[w*64 +  0+l16]=(f32x2){s[0],s2[0]};
    if(lg==1) red[w*64 + 16+l16]=(f32x2){s[1],s2[1]};
    if(lg==2) red[w*64 + 32+l16]=(f32x2){s[2],s2[2]};
    if(lg==3) red[w*64 + 48+l16]=(f32x2){s[3],s2[3]};
    __syncthreads();
    float mean[4], rstd[4];
    #pragma unroll
    for(int tt=0;tt<4;++tt){
      float S=0.f,S2=0.f;
      #pragma unroll
      for(int w2=0;w2<4;++w2){ f32x2 v=red[w2*64+16*tt+l16]; S+=v.x; S2+=v.y; }
      mean[tt]=S*(1.f/192.f);
      rstd[tt]=rsqrtf(S2*(1.f/192.f)-mean[tt]*mean[tt]+1e-5f);
    }
    #pragma unroll
    for(int mt=0;mt<3;++mt){
      const f32x4 g4=*(const f32x4*)(gg+48*w+16*mt+4*lg);
      const f32x4 b4=*(const f32x4*)(bbv+48*w+16*mt+4*lg);
      #pragma unroll
      for(int tt=0;tt<4;++tt){
        u16x4 pk;
        #pragma unroll
        for(int r=0;r<4;++r) pk[r]=f2b((t[mt][tt][r]-mean[tt])*rstd[tt]*g4[r]+b4[r]);
        *(u16x4*)(sm+sa_off(16*tt+l16,(48*w+16*mt+4*lg)*2))=pk;
      }
    }
  };

  layernorm(ln1g, ln1b);
  __syncthreads();   // h visible

  // ---- QKV producer: wave w -> ct=w>>1 (ch-half of head), tok-tiles {2(w&1),+1} ----
  // Weight fragments batched 9-at-a-time (3 ks) to keep loads in flight.
  const int ct=w>>1, tbase=2*(w&1);
  auto c1=[&](int hh){
    f32x4 qa[2],ka[2],va[2];
    #pragma unroll
    for(int i=0;i<2;++i){ qa[i]=(f32x4){0,0,0,0}; ka[i]=(f32x4){0,0,0,0}; va[i]=(f32x4){0,0,0,0}; }
    #pragma unroll
    for(int hf=0;hf<2;++hf){
      bf16x8 wq[3],wk[3],wv[3];
      #pragma unroll
      for(int k3=0;k3<3;++k3){
        const int ks=hf*3+k3;
        wq[k3]=*(const bf16x8*)(wqkvT+(      hh*32+ct*16+l16)*192+ks*32+lg*8);
        wk[k3]=*(const bf16x8*)(wqkvT+(192 + hh*32+ct*16+l16)*192+ks*32+lg*8);
        wv[k3]=*(const bf16x8*)(wqkvT+(384 + hh*32+ct*16+l16)*192+ks*32+lg*8);
      }
      #pragma unroll
      for(int k3=0;k3<3;++k3){
        const int ks=hf*3+k3;
        bf16x8 hfrag[2];
        #pragma unroll
        for(int i=0;i<2;++i) hfrag[i]=*(const bf16x8*)(sm+sa_off(16*(tbase+i)+l16, ks*64+lg*16));
        #pragma unroll
        for(int i=0;i<2;++i){
          qa[i]=__builtin_amdgcn_mfma_f32_16x16x32_bf16(wq[k3],hfrag[i],qa[i],0,0,0);  // D[qch][tok]
          ka[i]=__builtin_amdgcn_mfma_f32_16x16x32_bf16(wk[k3],hfrag[i],ka[i],0,0,0);
          va[i]=__builtin_amdgcn_mfma_f32_16x16x32_bf16(hfrag[i],wv[k3],va[i],0,0,0);  // D[tok][vch]
        }
      }
    }
    const f32x4 bq4=*(const f32x4*)(bqkv+      hh*32+ct*16+4*lg);
    const f32x4 bk4=*(const f32x4*)(bqkv+192 + hh*32+ct*16+4*lg);
    const float bv =bqkv[384 + hh*32+ct*16+l16];
    #pragma unroll
    for(int i=0;i<2;++i){
      const int tok=16*(tbase+i)+l16;
      u16x4 pq,pk,pv;
      #pragma unroll
      for(int r=0;r<4;++r){
        pq[r]=f2b(qa[i][r]+bq4[r]);
        pk[r]=f2b(ka[i][r]+bk4[r]);
        pv[r]=f2b(va[i][r]+bv);
      }
      *(u16x4*)(sm+qp_off(RQ_B,tok,32*ct+8*lg))=pq;                  // Q[tok][qch]
      *(u16x4*)(sm+qp_off(RK_B,tok,32*ct+8*lg))=pk;                  // K[tok][qch]
      *(u16x4*)(sm+vt_off(ct*16+l16,(16*(tbase+i)+4*lg)*2))=pv;      // VT[vch][tok]
    }
  };

  c1(0);
  __syncthreads();

  const float SM_C = 0.25503487f;  // log2(e)/sqrt(32), applied in f32 at exp2
  #pragma unroll 1
  for(int h=0;h<6;++h){
    // ---- S^T = K.Q (A=K rows=ktok, B=Q col=own q) ; softmax in-register ----
    {
      const int q=16*w+l16;
      const bf16x8 bqf=*(const bf16x8*)(sm+qp_off(RQ_B,q,lg*16));
      f32x4 sv[4];
      #pragma unroll
      for(int kt=0;kt<4;++kt){
        const bf16x8 akf=*(const bf16x8*)(sm+qp_off(RK_B,16*kt+l16,lg*16));
        sv[kt]=__builtin_amdgcn_mfma_f32_16x16x32_bf16(akf,bqf,(f32x4){0,0,0,0},0,0,0);
      }
      float mx=-3.0e38f;
      #pragma unroll
      for(int kt=0;kt<4;++kt){
        #pragma unroll
        for(int r=0;r<4;++r) mx=fmaxf(mx,sv[kt][r]);
      }
      mx=fmaxf(mx,__shfl_xor(mx,16)); mx=fmaxf(mx,__shfl_xor(mx,32));
      float sum=0.f;
      #pragma unroll
      for(int kt=0;kt<4;++kt){
        #pragma unroll
        for(int r=0;r<4;++r){ float e=exp2f((sv[kt][r]-mx)*SM_C); sv[kt][r]=e; sum+=e; }
      }
      sum+=__shfl_xor(sum,16); sum+=__shfl_xor(sum,32);
      const float rs=1.f/sum;
      U64 pk0,pk1,pk2,pk3;
      #pragma unroll
      for(int r=0;r<4;++r){ pk0.v[r]=f2b(sv[0][r]*rs); pk1.v[r]=f2b(sv[1][r]*rs);
                            pk2.v[r]=f2b(sv[2][r]*rs); pk3.v[r]=f2b(sv[3][r]*rs); }
      const int srcA = ((lg&1)<<5) + l16, srcB = srcA + 16;
      unsigned long long rA0=__shfl(pk0.u,srcA), rB0=__shfl(pk0.u,srcB);
      unsigned long long rA1=__shfl(pk1.u,srcA), rB1=__shfl(pk1.u,srcB);
      unsigned long long rA2=__shfl(pk2.u,srcA), rB2=__shfl(pk2.u,srcB);
      unsigned long long rA3=__shfl(pk3.u,srcA), rB3=__shfl(pk3.u,srcB);
      U128 pf0, pf1;
      pf0.q[0]=(lg<2)?rA0:rA1;  pf0.q[1]=(lg<2)?rB0:rB1;   // ktok 0..31
      pf1.q[0]=(lg<2)?rA2:rA3;  pf1.q[1]=(lg<2)?rB2:rB3;   // ktok 32..63
      // ---- PV: A=VT (rows d), B=P (col=own q) -> D[d][q]; write O[q][d] ----
      f32x4 ov[2]={(f32x4){0,0,0,0},(f32x4){0,0,0,0}};
      #pragma unroll
      for(int dt=0;dt<2;++dt){
        const bf16x8 av0=*(const bf16x8*)(sm+vt_off(16*dt+l16,lg*16));
        const bf16x8 av1=*(const bf16x8*)(sm+vt_off(16*dt+l16,64+lg*16));
        ov[dt]=__builtin_amdgcn_mfma_f32_16x16x32_bf16(av0,pf0.b,ov[dt],0,0,0);
        ov[dt]=__builtin_amdgcn_mfma_f32_16x16x32_bf16(av1,pf1.b,ov[dt],0,0,0);
      }
      #pragma unroll
      for(int dt=0;dt<2;++dt){
        u16x4 po;
        #pragma unroll
        for(int r=0;r<4;++r) po[r]=f2b(ov[dt][r]);
        *(u16x4*)(sm+qp_off(RO_B,q,32*dt+8*lg))=po;   // own q row
      }
    }
    __syncthreads();   // O visible; Q/K/VT reads done
    // ---- proj accumulate directly into t: A=Wproj rows=own outch, B=O col=tok ----
    {
      bf16x8 aw[3];
      #pragma unroll
      for(int mt=0;mt<3;++mt) aw[mt]=*(const bf16x8*)(wprojT+(16*(3*w+mt)+l16)*192+h*32+lg*8);
      bf16x8 bo[4];
      #pragma unroll
      for(int tt=0;tt<4;++tt) bo[tt]=*(const bf16x8*)(sm+qp_off(RO_B,16*tt+l16,lg*16));
      #pragma unroll
      for(int mt=0;mt<3;++mt){
        #pragma unroll
        for(int tt=0;tt<4;++tt)
          t[mt][tt]=__builtin_amdgcn_mfma_f32_16x16x32_bf16(aw[mt],bo[tt],t[mt][tt],0,0,0);
      }
    }
    if(h<5){ c1(h+1); __syncthreads(); }
  }

  // ---- proj bias once ----
  #pragma unroll
  for(int mt=0;mt<3;++mt){
    const f32x4 bp=*(const f32x4*)(bproj+48*w+16*mt+4*lg);
    #pragma unroll
    for(int tt=0;tt<4;++tt) t[mt][tt]+=bp;
  }

  // ---- LN2 (red overlays RQ; all Q reads finished) ----
  layernorm(ln2g, ln2b);
  __syncthreads();   // h2 visible; attn buffers dead -> G area free

  // ---- MLP: 12 chunks of 64 mch, double-buffered G (2x8192), 1 barrier/chunk ----
  auto mlp1=[&](int qc){
    char* gbuf = sm + RG_B + (qc&1)*8192;
    bf16x8 aw[6];
    #pragma unroll
    for(int ks=0;ks<6;++ks) aw[ks]=*(const bf16x8*)(wmlp1T+(qc*64+16*w+l16)*192+ks*32+lg*8);
    f32x4 g[4];
    #pragma unroll
    for(int tt=0;tt<4;++tt) g[tt]=(f32x4){0,0,0,0};
    #pragma unroll
    for(int ks=0;ks<6;++ks){
      #pragma unroll
      for(int tt=0;tt<4;++tt){
        const bf16x8 bh2=*(const bf16x8*)(sm+sa_off(16*tt+l16,ks*64+lg*16));
        g[tt]=__builtin_amdgcn_mfma_f32_16x16x32_bf16(aw[ks],bh2,g[tt],0,0,0);
      }
    }
    const f32x4 b1=*(const f32x4*)(bmlp1+qc*64+16*w+4*lg);
    #pragma unroll
    for(int tt=0;tt<4;++tt){
      u16x4 pg;
      #pragma unroll
      for(int r=0;r<4;++r){
        const float xv=g[tt][r]+b1[r];
        const float e=exp2f(-2.4554664f*xv);        // gelu ~ x*sigmoid(1.702x)
        pg[r]=f2b(xv*__builtin_amdgcn_rcpf(1.f+e));
      }
      *(u16x4*)(gbuf+gq_off(16*tt+l16, 32*w+8*lg))=pg;   // G[tok][mch-local]
    }
  };
  auto mlp2=[&](int qc){
    const char* gbuf = sm + RG_B + (qc&1)*8192;
    bf16x8 aw2[2][3];
    #pragma unroll
    for(int ks2=0;ks2<2;++ks2)
      #pragma unroll
      for(int mt=0;mt<3;++mt)
        aw2[ks2][mt]=*(const bf16x8*)(wmlp2T+(16*(3*w+mt)+l16)*768+qc*64+ks2*32+lg*8);
    #pragma unroll
    for(int ks2=0;ks2<2;++ks2){
      bf16x8 bg[4];
      #pragma unroll
      for(int tt=0;tt<4;++tt) bg[tt]=*(const bf16x8*)(gbuf+gq_off(16*tt+l16,ks2*64+lg*16));
      #pragma unroll
      for(int mt=0;mt<3;++mt){
        #pragma unroll
        for(int tt=0;tt<4;++tt)
          t[mt][tt]=__builtin_amdgcn_mfma_f32_16x16x32_bf16(aw2[ks2][mt],bg[tt],t[mt][tt],0,0,0);
      }
    }
  };

  mlp1(0);
  __syncthreads();             // G(0) visible
  #pragma unroll 1
  for(int qc=0;qc<12;++qc){
    mlp2(qc);                  // consume buf[qc&1]
    if(qc<11) mlp1(qc+1);      // produce buf[(qc+1)&1]
    __syncthreads();           // G(qc+1) visible; G(qc) reads done
  }

  // ---- Final: out = t + bmlp2 (regular stores) ----
  #pragma unroll
  for(int mt=0;mt<3;++mt){
    const f32x4 b2=*(const f32x4*)(bmlp2+48*w+16*mt+4*lg);
    #pragma unroll
    for(int tt=0;tt<4;++tt){
      const int T=16*tt+l16, tp=(T>>3)*256+(T&7);
      #pragma unroll
      for(int r=0;r<4;++r)
        outp[imgoff+(size_t)(48*w+16*mt+4*lg+r)*65536+tp]=t[mt][tt][r]+b2[r];
    }
  }
}

extern "C" void kernel_launch(void* const* d_in, const int* in_sizes, int n_in,
                              void* d_out, int out_size, void* d_ws, size_t ws_size,
                              hipStream_t stream) {
  const float* x      = (const float*)d_in[0];
  const float* w_qkv  = (const float*)d_in[1];
  const float* b_qkv  = (const float*)d_in[2];
  const float* w_proj = (const float*)d_in[3];
  const float* b_proj = (const float*)d_in[4];
  const float* ln1g   = (const float*)d_in[5];
  const float* ln1b   = (const float*)d_in[6];
  const float* ln2g   = (const float*)d_in[7];
  const float* ln2b   = (const float*)d_in[8];
  const float* w_mlp1 = (const float*)d_in[9];
  const float* b_mlp1 = (const float*)d_in[10];
  const float* w_mlp2 = (const float*)d_in[11];
  const float* b_mlp2 = (const float*)d_in[12];
  float* out = (float*)d_out;
  unsigned short* wsu = (unsigned short*)d_ws;

  prep_weights<<<dim3(1728), dim3(256), 0, stream>>>(w_qkv, w_proj, w_mlp1, w_mlp2, wsu);
  winblock<<<dim3(4096), dim3(256), 0, stream>>>(
      x, out, b_qkv, b_proj, ln1g, ln1b, ln2g, ln2b, b_mlp1, b_mlp2,
      wsu, wsu+110592, wsu+147456, wsu+294912);
}